// Round 1
// baseline (2828.888 us; speedup 1.0000x reference)
//
#include <hip/hip_runtime.h>
#include <hip/hip_bf16.h>

// 3-layer GCN on MI355X.
//   layer l: h = act(prev) @ Wl ; agg[i] = sum_{e:(s->i)} dinv[s]*dinv[i]*h[s]
//            + dinv[i]^2*h[i] ; y = agg + b ; (BN -> scale/shift fused into
//            next GEMM's A-load together with ReLU)
// All scratch in d_ws; zero-init via hipMemsetAsync (graph-capture safe).

__global__ void count_deg_kernel(const int* __restrict__ dst, int E,
                                 int* __restrict__ deg) {
    int e = blockIdx.x * blockDim.x + threadIdx.x;
    if (e < E) atomicAdd(deg + dst[e], 1);
}

// in-place int degree -> float rsqrt(deg + 1)   (+1 = self loop)
__global__ void dinv_kernel(int* __restrict__ degio, int n) {
    int i = blockIdx.x * blockDim.x + threadIdx.x;
    if (i < n) {
        float d = (float)(degio[i] + 1);
        reinterpret_cast<float*>(degio)[i] = rsqrtf(d);
    }
}

// C[n x NC] = act(A[n x 128]) * W[128 x NC]; act = identity or BN(scale,shift)+ReLU
// block: 64 rows x 64 cols tile, 256 threads, 4x4 micro-tile per thread.
template <int NC, bool TRANS>
__global__ __launch_bounds__(256) void gemm_k128(
    const float* __restrict__ A, const float* __restrict__ W,
    float* __restrict__ C, int n, const float* __restrict__ ss) {
    __shared__ float As[32][64];  // [k][row]
    __shared__ float Ws[32][64];  // [k][col]
    const int tid = threadIdx.x;
    const int row0 = blockIdx.x * 64;
    const int col0 = blockIdx.y * 64;
    const int tx = tid & 15, ty = tid >> 4;
    const int ar = tid >> 3;        // 0..31 (row within half-tile)
    const int akq = (tid & 7) * 4;  // k quad
    const int wk = tid >> 4;        // 0..15
    const int wjq = (tid & 15) * 4; // col quad
    float acc[4][4] = {};

    for (int kb = 0; kb < 128; kb += 32) {
#pragma unroll
        for (int half = 0; half < 2; ++half) {
            int row = row0 + ar + half * 32;
            float4 v = make_float4(0.f, 0.f, 0.f, 0.f);
            if (row < n)
                v = *reinterpret_cast<const float4*>(A + (size_t)row * 128 + kb + akq);
            if (TRANS) {
                float4 sc = *reinterpret_cast<const float4*>(ss + kb + akq);
                float4 sh = *reinterpret_cast<const float4*>(ss + 128 + kb + akq);
                v.x = fmaxf(fmaf(v.x, sc.x, sh.x), 0.f);
                v.y = fmaxf(fmaf(v.y, sc.y, sh.y), 0.f);
                v.z = fmaxf(fmaf(v.z, sc.z, sh.z), 0.f);
                v.w = fmaxf(fmaf(v.w, sc.w, sh.w), 0.f);
            }
            As[akq + 0][ar + half * 32] = v.x;
            As[akq + 1][ar + half * 32] = v.y;
            As[akq + 2][ar + half * 32] = v.z;
            As[akq + 3][ar + half * 32] = v.w;
        }
#pragma unroll
        for (int half = 0; half < 2; ++half) {
            int k = kb + wk + half * 16;
            float4 w = *reinterpret_cast<const float4*>(W + (size_t)k * NC + col0 + wjq);
            *reinterpret_cast<float4*>(&Ws[wk + half * 16][wjq]) = w;
        }
        __syncthreads();
#pragma unroll
        for (int kk = 0; kk < 32; ++kk) {
            float4 a4 = *reinterpret_cast<const float4*>(&As[kk][ty * 4]);
            float4 b4 = *reinterpret_cast<const float4*>(&Ws[kk][tx * 4]);
            float av[4] = {a4.x, a4.y, a4.z, a4.w};
            float bv[4] = {b4.x, b4.y, b4.z, b4.w};
#pragma unroll
            for (int r = 0; r < 4; ++r)
#pragma unroll
                for (int c = 0; c < 4; ++c)
                    acc[r][c] = fmaf(av[r], bv[c], acc[r][c]);
        }
        __syncthreads();
    }
#pragma unroll
    for (int r = 0; r < 4; ++r) {
        int row = row0 + ty * 4 + r;
        if (row < n) {
            float4 o = make_float4(acc[r][0], acc[r][1], acc[r][2], acc[r][3]);
            *reinterpret_cast<float4*>(C + (size_t)row * NC + col0 + tx * 4) = o;
        }
    }
}

// out[dst] += dinv[src]*dinv[dst] * h[src]   (float4 per thread, F/4 threads/edge)
template <int F>
__global__ __launch_bounds__(256) void scatter_kernel(
    const int* __restrict__ src, const int* __restrict__ dst, int E,
    const float* __restrict__ dinv, const float* __restrict__ h,
    float* __restrict__ out) {
    const int PER = F / 4;
    int gid = blockIdx.x * blockDim.x + threadIdx.x;
    int e = gid / PER;
    if (e >= E) return;
    int fq = (gid % PER) * 4;
    int s = src[e], d = dst[e];
    float w = dinv[s] * dinv[d];
    float4 v = *reinterpret_cast<const float4*>(h + (size_t)s * F + fq);
    float* o = out + (size_t)d * F + fq;
    atomicAdd(o + 0, v.x * w);
    atomicAdd(o + 1, v.y * w);
    atomicAdd(o + 2, v.z * w);
    atomicAdd(o + 3, v.w * w);
}

// agg += dinv^2 * h + bias (in place); optionally accumulate per-feature
// sum / sumsq for BN into stats[0..F), stats[F..2F)
template <int F, bool STATS>
__global__ void epilogue_kernel(float* __restrict__ agg,
                                const float* __restrict__ h,
                                const float* __restrict__ dinv,
                                const float* __restrict__ bias, int n,
                                float* __restrict__ stats) {
    int f = threadIdx.x;
    float bf = bias[f];
    float s = 0.f, sq = 0.f;
    for (int i = blockIdx.x * blockDim.y + threadIdx.y; i < n;
         i += gridDim.x * blockDim.y) {
        float di = dinv[i];
        size_t idx = (size_t)i * F + f;
        float y = fmaf(di * di, h[idx], agg[idx]) + bf;
        agg[idx] = y;
        if (STATS) {
            s += y;
            sq = fmaf(y, y, sq);
        }
    }
    if (STATS) {
        atomicAdd(stats + f, s);
        atomicAdd(stats + F + f, sq);
    }
}

// scale = g * rsqrt(var+eps); shift = be - mean*scale   (F=128 both BN layers)
__global__ void finalize_kernel(const float* __restrict__ stats,
                                const float* __restrict__ g,
                                const float* __restrict__ be, float invn,
                                float* __restrict__ ss) {
    int f = threadIdx.x;
    float mean = stats[f] * invn;
    float var = fmaf(-mean, mean, stats[128 + f] * invn);
    float sc = g[f] * rsqrtf(var + 1e-5f);
    ss[f] = sc;
    ss[128 + f] = fmaf(-mean, sc, be[f]);
}

extern "C" void kernel_launch(void* const* d_in, const int* in_sizes, int n_in,
                              void* d_out, int out_size, void* d_ws,
                              size_t ws_size, hipStream_t stream) {
    const float* x   = (const float*)d_in[0];
    const int*   ei  = (const int*)d_in[1];
    const float* W1  = (const float*)d_in[2];
    const float* b1  = (const float*)d_in[3];
    const float* g1  = (const float*)d_in[4];
    const float* be1 = (const float*)d_in[5];
    const float* W2  = (const float*)d_in[6];
    const float* b2  = (const float*)d_in[7];
    const float* g2  = (const float*)d_in[8];
    const float* be2 = (const float*)d_in[9];
    const float* W3  = (const float*)d_in[10];
    const float* b3  = (const float*)d_in[11];
    float* out = (float*)d_out;

    const int n = in_sizes[0] / 128;
    const int E = in_sizes[1] / 2;
    const int* src = ei;
    const int* dst = ei + E;

    float* wsf   = (float*)d_ws;
    float* dinv  = wsf;                      // n floats (ints during counting)
    float* stats = wsf + n;                  // 256
    float* ss    = stats + 256;              // 256 (scale|shift)
    float* bufA  = ss + 256;                 // n*128
    float* bufB  = bufA + (size_t)n * 128;   // n*128

    // degrees -> dinv
    hipMemsetAsync(dinv, 0, (size_t)n * 4, stream);
    count_deg_kernel<<<(E + 255) / 256, 256, 0, stream>>>(dst, E, (int*)dinv);
    dinv_kernel<<<(n + 255) / 256, 256, 0, stream>>>((int*)dinv, n);

    dim3 gemmGrid128((n + 63) / 64, 2);
    dim3 gemmGrid64((n + 63) / 64, 1);
    const int scat128 = (E * 32 + 255) / 256;
    const int scat64 = (E * 16 + 255) / 256;

    // ---- layer 1 ----
    gemm_k128<128, false><<<gemmGrid128, 256, 0, stream>>>(x, W1, bufA, n, nullptr);
    hipMemsetAsync(bufB, 0, (size_t)n * 128 * 4, stream);
    scatter_kernel<128><<<scat128, 256, 0, stream>>>(src, dst, E, dinv, bufA, bufB);
    hipMemsetAsync(stats, 0, 256 * 4, stream);
    epilogue_kernel<128, true><<<512, dim3(128, 2), 0, stream>>>(bufB, bufA, dinv, b1, n, stats);
    finalize_kernel<<<1, 128, 0, stream>>>(stats, g1, be1, 1.0f / n, ss);

    // ---- layer 2 ----
    gemm_k128<128, true><<<gemmGrid128, 256, 0, stream>>>(bufB, W2, bufA, n, ss);
    hipMemsetAsync(bufB, 0, (size_t)n * 128 * 4, stream);
    scatter_kernel<128><<<scat128, 256, 0, stream>>>(src, dst, E, dinv, bufA, bufB);
    hipMemsetAsync(stats, 0, 256 * 4, stream);
    epilogue_kernel<128, true><<<512, dim3(128, 2), 0, stream>>>(bufB, bufA, dinv, b2, n, stats);
    finalize_kernel<<<1, 128, 0, stream>>>(stats, g2, be2, 1.0f / n, ss);

    // ---- layer 3 ----
    gemm_k128<64, true><<<gemmGrid64, 256, 0, stream>>>(bufB, W3, bufA, n, ss);
    hipMemsetAsync(out, 0, (size_t)n * 64 * 4, stream);
    scatter_kernel<64><<<scat64, 256, 0, stream>>>(src, dst, E, dinv, bufA, out);
    epilogue_kernel<64, false><<<512, dim3(64, 4), 0, stream>>>(out, bufA, dinv, b3, n, nullptr);
}

// Round 2
// 732.154 us; speedup vs baseline: 3.8638x; 3.8638x over previous
//
#include <hip/hip_runtime.h>
#include <hip/hip_bf16.h>

// 3-layer GCN, CSR gather-reduce formulation (no float atomics).
//   hs = dinv[row] * (act(prev) @ W)          (GEMM, act = BN+ReLU fused)
//   y[i] = dinv[i]*(hs[i] + sum_{e: s->i} hs[s]) + b
// CSR built per call: count degrees into rowptr+1, in-place scan,
// destructive-cursor placement (rowptr[i] becomes end-of-row i).

__global__ void count_deg_kernel(const int* __restrict__ dst, int E,
                                 int* __restrict__ rowptr1 /* rowptr+1 */) {
    int e = blockIdx.x * blockDim.x + threadIdx.x;
    if (e < E) atomicAdd(rowptr1 + dst[e], 1);
}

// dinv[i] = rsqrt(deg_i + 1); deg_i lives at rowptr[i+1] (pre-scan)
__global__ void dinv_kernel(const int* __restrict__ rowptr, int n,
                            float* __restrict__ dinv) {
    int i = blockIdx.x * blockDim.x + threadIdx.x;
    if (i < n) dinv[i] = rsqrtf((float)(rowptr[i + 1] + 1));
}

// single-block in-place inclusive scan of rowptr[0..n]  (rowptr[0]==0)
__global__ void scan_kernel(int* __restrict__ rowptr, int n) {
    __shared__ int sh[256];
    const int t = threadIdx.x;
    int base = 0;
    const int total = n + 1;
    for (int start = 0; start < total; start += 256) {
        int i = start + t;
        int v = (i < total) ? rowptr[i] : 0;
        sh[t] = v;
        __syncthreads();
#pragma unroll
        for (int off = 1; off < 256; off <<= 1) {
            int add = (t >= off) ? sh[t - off] : 0;
            __syncthreads();
            sh[t] += add;
            __syncthreads();
        }
        if (i < total) rowptr[i] = base + sh[t];
        base += sh[255];
        __syncthreads();
    }
}

// destructive cursor: rowptr[d] advances start->end while placing srcs
__global__ void csr_build_kernel(const int* __restrict__ src,
                                 const int* __restrict__ dst, int E,
                                 int* __restrict__ rowptr,
                                 int* __restrict__ csr_src) {
    int e = blockIdx.x * blockDim.x + threadIdx.x;
    if (e < E) {
        int pos = atomicAdd(rowptr + dst[e], 1);
        csr_src[pos] = src[e];
    }
}

// C[n x NC] = dinv[row] * (act(A[n x 128]) * W[128 x NC])
// act = identity or BN(scale,shift)+ReLU. 64x64 tile, 256 thr, 4x4 micro.
template <int NC, bool TRANS>
__global__ __launch_bounds__(256) void gemm_k128(
    const float* __restrict__ A, const float* __restrict__ W,
    float* __restrict__ C, int n, const float* __restrict__ ss,
    const float* __restrict__ dinv) {
    __shared__ float As[32][64];  // [k][row]
    __shared__ float Ws[32][64];  // [k][col]
    const int tid = threadIdx.x;
    const int row0 = blockIdx.x * 64;
    const int col0 = blockIdx.y * 64;
    const int tx = tid & 15, ty = tid >> 4;
    const int ar = tid >> 3;        // 0..31
    const int akq = (tid & 7) * 4;  // k quad
    const int wk = tid >> 4;        // 0..15
    const int wjq = (tid & 15) * 4; // col quad
    float acc[4][4] = {};

    for (int kb = 0; kb < 128; kb += 32) {
#pragma unroll
        for (int half = 0; half < 2; ++half) {
            int row = row0 + ar + half * 32;
            float4 v = make_float4(0.f, 0.f, 0.f, 0.f);
            if (row < n)
                v = *reinterpret_cast<const float4*>(A + (size_t)row * 128 + kb + akq);
            if (TRANS) {
                float4 sc = *reinterpret_cast<const float4*>(ss + kb + akq);
                float4 sh = *reinterpret_cast<const float4*>(ss + 128 + kb + akq);
                v.x = fmaxf(fmaf(v.x, sc.x, sh.x), 0.f);
                v.y = fmaxf(fmaf(v.y, sc.y, sh.y), 0.f);
                v.z = fmaxf(fmaf(v.z, sc.z, sh.z), 0.f);
                v.w = fmaxf(fmaf(v.w, sc.w, sh.w), 0.f);
            }
            As[akq + 0][ar + half * 32] = v.x;
            As[akq + 1][ar + half * 32] = v.y;
            As[akq + 2][ar + half * 32] = v.z;
            As[akq + 3][ar + half * 32] = v.w;
        }
#pragma unroll
        for (int half = 0; half < 2; ++half) {
            int k = kb + wk + half * 16;
            float4 w = *reinterpret_cast<const float4*>(W + (size_t)k * NC + col0 + wjq);
            *reinterpret_cast<float4*>(&Ws[wk + half * 16][wjq]) = w;
        }
        __syncthreads();
#pragma unroll
        for (int kk = 0; kk < 32; ++kk) {
            float4 a4 = *reinterpret_cast<const float4*>(&As[kk][ty * 4]);
            float4 b4 = *reinterpret_cast<const float4*>(&Ws[kk][tx * 4]);
            float av[4] = {a4.x, a4.y, a4.z, a4.w};
            float bv[4] = {b4.x, b4.y, b4.z, b4.w};
#pragma unroll
            for (int r = 0; r < 4; ++r)
#pragma unroll
                for (int c = 0; c < 4; ++c)
                    acc[r][c] = fmaf(av[r], bv[c], acc[r][c]);
        }
        __syncthreads();
    }
#pragma unroll
    for (int r = 0; r < 4; ++r) {
        int row = row0 + ty * 4 + r;
        if (row < n) {
            float di = dinv[row];
            float4 o = make_float4(acc[r][0] * di, acc[r][1] * di,
                                   acc[r][2] * di, acc[r][3] * di);
            *reinterpret_cast<float4*>(C + (size_t)row * NC + col0 + tx * 4) = o;
        }
    }
}

// y[i] = dinv[i]*(hs[i] + sum_{e in row i} hs[csr_src[e]]) + bias
// one LANES-lane group per node, float4 per lane; optional BN stats.
// NOTE: rowptr is POST-BUILD (rowptr[i] = end of row i; start = rowptr[i-1]).
template <int F, bool STATS>
__global__ __launch_bounds__(256) void aggregate_kernel(
    const float* __restrict__ hs, const int* __restrict__ csr_src,
    const int* __restrict__ rowptr, const float* __restrict__ dinv,
    const float* __restrict__ bias, float* __restrict__ out, int n,
    float* __restrict__ stats) {
    const int LANES = F / 4;
    const int GROUPS = 256 / LANES;
    const int lane = threadIdx.x % LANES;
    const int grp = threadIdx.x / LANES;
    const int fq = lane * 4;
    const float4 b4 = *reinterpret_cast<const float4*>(bias + fq);
    float s[4] = {}, sq[4] = {};

    for (int i = blockIdx.x * GROUPS + grp; i < n; i += gridDim.x * GROUPS) {
        int beg = (i == 0) ? 0 : rowptr[i - 1];
        int end = rowptr[i];
        float4 acc = *reinterpret_cast<const float4*>(hs + (size_t)i * F + fq);
        int e = beg;
        for (; e + 1 < end; e += 2) {
            int s0 = csr_src[e], s1 = csr_src[e + 1];
            float4 v0 = *reinterpret_cast<const float4*>(hs + (size_t)s0 * F + fq);
            float4 v1 = *reinterpret_cast<const float4*>(hs + (size_t)s1 * F + fq);
            acc.x += v0.x + v1.x;
            acc.y += v0.y + v1.y;
            acc.z += v0.z + v1.z;
            acc.w += v0.w + v1.w;
        }
        if (e < end) {
            int s0 = csr_src[e];
            float4 v0 = *reinterpret_cast<const float4*>(hs + (size_t)s0 * F + fq);
            acc.x += v0.x;
            acc.y += v0.y;
            acc.z += v0.z;
            acc.w += v0.w;
        }
        float di = dinv[i];
        float4 y;
        y.x = fmaf(di, acc.x, b4.x);
        y.y = fmaf(di, acc.y, b4.y);
        y.z = fmaf(di, acc.z, b4.z);
        y.w = fmaf(di, acc.w, b4.w);
        *reinterpret_cast<float4*>(out + (size_t)i * F + fq) = y;
        if (STATS) {
            s[0] += y.x; sq[0] = fmaf(y.x, y.x, sq[0]);
            s[1] += y.y; sq[1] = fmaf(y.y, y.y, sq[1]);
            s[2] += y.z; sq[2] = fmaf(y.z, y.z, sq[2]);
            s[3] += y.w; sq[3] = fmaf(y.w, y.w, sq[3]);
        }
    }
    if (STATS) {
        __shared__ float sred[32][8];  // [lane][group]  (F==128 path only)
#pragma unroll
        for (int q = 0; q < 8; ++q) {
            float v = (q < 4) ? s[q] : sq[q - 4];
            sred[lane][grp] = v;
            __syncthreads();
            if (grp == 0) {
                float t = 0.f;
#pragma unroll
                for (int g = 0; g < 8; ++g) t += sred[lane][g];
                int f = fq + (q & 3);
                atomicAdd(stats + ((q < 4) ? f : 128 + f), t);
            }
            __syncthreads();
        }
    }
}

// scale = g * rsqrt(var+eps); shift = be - mean*scale
__global__ void finalize_kernel(const float* __restrict__ stats,
                                const float* __restrict__ g,
                                const float* __restrict__ be, float invn,
                                float* __restrict__ ss) {
    int f = threadIdx.x;
    float mean = stats[f] * invn;
    float var = fmaf(-mean, mean, stats[128 + f] * invn);
    float sc = g[f] * rsqrtf(var + 1e-5f);
    ss[f] = sc;
    ss[128 + f] = fmaf(-mean, sc, be[f]);
}

extern "C" void kernel_launch(void* const* d_in, const int* in_sizes, int n_in,
                              void* d_out, int out_size, void* d_ws,
                              size_t ws_size, hipStream_t stream) {
    const float* x   = (const float*)d_in[0];
    const int*   ei  = (const int*)d_in[1];
    const float* W1  = (const float*)d_in[2];
    const float* b1  = (const float*)d_in[3];
    const float* g1  = (const float*)d_in[4];
    const float* be1 = (const float*)d_in[5];
    const float* W2  = (const float*)d_in[6];
    const float* b2  = (const float*)d_in[7];
    const float* g2  = (const float*)d_in[8];
    const float* be2 = (const float*)d_in[9];
    const float* W3  = (const float*)d_in[10];
    const float* b3  = (const float*)d_in[11];
    float* out = (float*)d_out;

    const int n = in_sizes[0] / 128;
    const int E = in_sizes[1] / 2;
    const int* src = ei;
    const int* dst = ei + E;

    float* wsf    = (float*)d_ws;
    float* dinv   = wsf;                     // n floats
    float* stats  = wsf + n;                 // 256
    float* ss     = stats + 256;             // 256
    int*   rowptr = (int*)(ss + 256);        // n+1 ints
    int*   csrsrc = rowptr + (n + 1);        // E ints
    float* bufA   = (float*)(csrsrc + E);    // n*128
    float* bufB   = bufA + (size_t)n * 128;  // n*128

    // ---- CSR build + dinv ----
    hipMemsetAsync(rowptr, 0, (size_t)(n + 1) * 4, stream);
    count_deg_kernel<<<(E + 255) / 256, 256, 0, stream>>>(dst, E, rowptr + 1);
    dinv_kernel<<<(n + 255) / 256, 256, 0, stream>>>(rowptr, n, dinv);
    scan_kernel<<<1, 256, 0, stream>>>(rowptr, n);
    csr_build_kernel<<<(E + 255) / 256, 256, 0, stream>>>(src, dst, E, rowptr, csrsrc);

    dim3 gemmGrid128((n + 63) / 64, 2);
    dim3 gemmGrid64((n + 63) / 64, 1);

    // ---- layer 1 ----
    gemm_k128<128, false><<<gemmGrid128, 256, 0, stream>>>(x, W1, bufA, n, nullptr, dinv);
    hipMemsetAsync(stats, 0, 256 * 4, stream);
    aggregate_kernel<128, true><<<512, 256, 0, stream>>>(bufA, csrsrc, rowptr, dinv, b1, bufB, n, stats);
    finalize_kernel<<<1, 128, 0, stream>>>(stats, g1, be1, 1.0f / n, ss);

    // ---- layer 2 ----
    gemm_k128<128, true><<<gemmGrid128, 256, 0, stream>>>(bufB, W2, bufA, n, ss, dinv);
    hipMemsetAsync(stats, 0, 256 * 4, stream);
    aggregate_kernel<128, true><<<512, 256, 0, stream>>>(bufA, csrsrc, rowptr, dinv, b2, bufB, n, stats);
    finalize_kernel<<<1, 128, 0, stream>>>(stats, g2, be2, 1.0f / n, ss);

    // ---- layer 3 ----
    gemm_k128<64, true><<<gemmGrid64, 256, 0, stream>>>(bufB, W3, bufA, n, ss, dinv);
    aggregate_kernel<64, false><<<512, 256, 0, stream>>>(bufA, csrsrc, rowptr, dinv, b3, out, n, nullptr);
}

// Round 3
// 535.458 us; speedup vs baseline: 5.2831x; 1.3673x over previous
//
#include <hip/hip_runtime.h>
#include <hip/hip_bf16.h>

// 3-layer GCN, CSR gather-reduce formulation (no float atomics).
//   hs = dinv[row] * (act(prev) @ W)          (GEMM, act = BN+ReLU fused)
//   y[i] = dinv[i]*(hs[i] + sum_{e: s->i} hs[s]) + b
// CSR built per call: count degrees -> 3-phase parallel scan ->
// destructive-cursor placement (rowptr[i] becomes end-of-row i).

__global__ void count_deg_kernel(const int* __restrict__ dst, int E,
                                 int* __restrict__ rowptr1 /* rowptr+1 */) {
    int e = blockIdx.x * blockDim.x + threadIdx.x;
    if (e < E) atomicAdd(rowptr1 + dst[e], 1);
}

// dinv[i] = rsqrt(deg_i + 1); deg_i lives at rowptr[i+1] (pre-scan)
__global__ void dinv_kernel(const int* __restrict__ rowptr, int n,
                            float* __restrict__ dinv) {
    int i = blockIdx.x * blockDim.x + threadIdx.x;
    if (i < n) dinv[i] = rsqrtf((float)(rowptr[i + 1] + 1));
}

// ---- 3-phase parallel inclusive scan over rowptr[0..total) ----
// phase A: per-block (2048-elem chunk) inclusive scan + chunk total
__global__ __launch_bounds__(256) void scanA_kernel(int* __restrict__ data,
                                                    int total,
                                                    int* __restrict__ bsum) {
    __shared__ int sh[256];
    const int t = threadIdx.x;
    const int base = blockIdx.x * 2048 + t * 8;
    int v[8];
    int run = 0;
#pragma unroll
    for (int j = 0; j < 8; ++j) {
        int idx = base + j;
        int x = (idx < total) ? data[idx] : 0;
        run += x;
        v[j] = run;
    }
    sh[t] = run;
    __syncthreads();
#pragma unroll
    for (int off = 1; off < 256; off <<= 1) {
        int add = (t >= off) ? sh[t - off] : 0;
        __syncthreads();
        sh[t] += add;
        __syncthreads();
    }
    int prev = (t > 0) ? sh[t - 1] : 0;
#pragma unroll
    for (int j = 0; j < 8; ++j) {
        int idx = base + j;
        if (idx < total) data[idx] = v[j] + prev;
    }
    if (t == 255) bsum[blockIdx.x] = sh[255];
}

// phase B: single small block scans the (<=64) block sums
__global__ void scanB_kernel(int* __restrict__ bsum, int nb) {
    __shared__ int sh[64];
    const int t = threadIdx.x;
    sh[t] = (t < nb) ? bsum[t] : 0;
    __syncthreads();
#pragma unroll
    for (int off = 1; off < 64; off <<= 1) {
        int add = (t >= off) ? sh[t - off] : 0;
        __syncthreads();
        sh[t] += add;
        __syncthreads();
    }
    if (t < nb) bsum[t] = sh[t];
}

// phase C: add preceding-chunk offsets
__global__ __launch_bounds__(256) void scanC_kernel(int* __restrict__ data,
                                                    int total,
                                                    const int* __restrict__ bsum) {
    if (blockIdx.x == 0) return;
    const int off = bsum[blockIdx.x - 1];
    const int base = blockIdx.x * 2048 + threadIdx.x * 8;
#pragma unroll
    for (int j = 0; j < 8; ++j) {
        int idx = base + j;
        if (idx < total) data[idx] += off;
    }
}

// destructive cursor: rowptr[d] advances start->end while placing srcs
__global__ void csr_build_kernel(const int* __restrict__ src,
                                 const int* __restrict__ dst, int E,
                                 int* __restrict__ rowptr,
                                 int* __restrict__ csr_src) {
    int e = blockIdx.x * blockDim.x + threadIdx.x;
    if (e < E) {
        int pos = atomicAdd(rowptr + dst[e], 1);
        csr_src[pos] = src[e];
    }
}

// C[n x NC] = dinv[row] * (act(A[n x 128]) * W[128 x NC])
// act = identity or BN(scale,shift)+ReLU. 64x64 tile, 256 thr, 4x4 micro.
template <int NC, bool TRANS>
__global__ __launch_bounds__(256) void gemm_k128(
    const float* __restrict__ A, const float* __restrict__ W,
    float* __restrict__ C, int n, const float* __restrict__ ss,
    const float* __restrict__ dinv) {
    __shared__ float As[32][64];  // [k][row]
    __shared__ float Ws[32][64];  // [k][col]
    const int tid = threadIdx.x;
    const int row0 = blockIdx.x * 64;
    const int col0 = blockIdx.y * 64;
    const int tx = tid & 15, ty = tid >> 4;
    const int ar = tid >> 3;        // 0..31
    const int akq = (tid & 7) * 4;  // k quad
    const int wk = tid >> 4;        // 0..15
    const int wjq = (tid & 15) * 4; // col quad
    float acc[4][4] = {};

    for (int kb = 0; kb < 128; kb += 32) {
#pragma unroll
        for (int half = 0; half < 2; ++half) {
            int row = row0 + ar + half * 32;
            float4 v = make_float4(0.f, 0.f, 0.f, 0.f);
            if (row < n)
                v = *reinterpret_cast<const float4*>(A + (size_t)row * 128 + kb + akq);
            if (TRANS) {
                float4 sc = *reinterpret_cast<const float4*>(ss + kb + akq);
                float4 sh = *reinterpret_cast<const float4*>(ss + 128 + kb + akq);
                v.x = fmaxf(fmaf(v.x, sc.x, sh.x), 0.f);
                v.y = fmaxf(fmaf(v.y, sc.y, sh.y), 0.f);
                v.z = fmaxf(fmaf(v.z, sc.z, sh.z), 0.f);
                v.w = fmaxf(fmaf(v.w, sc.w, sh.w), 0.f);
            }
            As[akq + 0][ar + half * 32] = v.x;
            As[akq + 1][ar + half * 32] = v.y;
            As[akq + 2][ar + half * 32] = v.z;
            As[akq + 3][ar + half * 32] = v.w;
        }
#pragma unroll
        for (int half = 0; half < 2; ++half) {
            int k = kb + wk + half * 16;
            float4 w = *reinterpret_cast<const float4*>(W + (size_t)k * NC + col0 + wjq);
            *reinterpret_cast<float4*>(&Ws[wk + half * 16][wjq]) = w;
        }
        __syncthreads();
#pragma unroll
        for (int kk = 0; kk < 32; ++kk) {
            float4 a4 = *reinterpret_cast<const float4*>(&As[kk][ty * 4]);
            float4 b4 = *reinterpret_cast<const float4*>(&Ws[kk][tx * 4]);
            float av[4] = {a4.x, a4.y, a4.z, a4.w};
            float bv[4] = {b4.x, b4.y, b4.z, b4.w};
#pragma unroll
            for (int r = 0; r < 4; ++r)
#pragma unroll
                for (int c = 0; c < 4; ++c)
                    acc[r][c] = fmaf(av[r], bv[c], acc[r][c]);
        }
        __syncthreads();
    }
#pragma unroll
    for (int r = 0; r < 4; ++r) {
        int row = row0 + ty * 4 + r;
        if (row < n) {
            float di = dinv[row];
            float4 o = make_float4(acc[r][0] * di, acc[r][1] * di,
                                   acc[r][2] * di, acc[r][3] * di);
            *reinterpret_cast<float4*>(C + (size_t)row * NC + col0 + tx * 4) = o;
        }
    }
}

// y[i] = dinv[i]*(hs[i] + sum_{e in row i} hs[csr_src[e]]) + bias
// one LANES-lane group per node, float4 per lane; optional BN stats.
// NOTE: rowptr is POST-BUILD (rowptr[i] = end of row i; start = rowptr[i-1]).
template <int F, bool STATS>
__global__ __launch_bounds__(256) void aggregate_kernel(
    const float* __restrict__ hs, const int* __restrict__ csr_src,
    const int* __restrict__ rowptr, const float* __restrict__ dinv,
    const float* __restrict__ bias, float* __restrict__ out, int n,
    float* __restrict__ stats) {
    const int LANES = F / 4;
    const int GROUPS = 256 / LANES;
    const int lane = threadIdx.x % LANES;
    const int grp = threadIdx.x / LANES;
    const int fq = lane * 4;
    const float4 b4 = *reinterpret_cast<const float4*>(bias + fq);
    float s[4] = {}, sq[4] = {};

    for (int i = blockIdx.x * GROUPS + grp; i < n; i += gridDim.x * GROUPS) {
        int beg = (i == 0) ? 0 : rowptr[i - 1];
        int end = rowptr[i];
        float4 acc = *reinterpret_cast<const float4*>(hs + (size_t)i * F + fq);
        int e = beg;
        for (; e + 1 < end; e += 2) {
            int s0 = csr_src[e], s1 = csr_src[e + 1];
            float4 v0 = *reinterpret_cast<const float4*>(hs + (size_t)s0 * F + fq);
            float4 v1 = *reinterpret_cast<const float4*>(hs + (size_t)s1 * F + fq);
            acc.x += v0.x + v1.x;
            acc.y += v0.y + v1.y;
            acc.z += v0.z + v1.z;
            acc.w += v0.w + v1.w;
        }
        if (e < end) {
            int s0 = csr_src[e];
            float4 v0 = *reinterpret_cast<const float4*>(hs + (size_t)s0 * F + fq);
            acc.x += v0.x;
            acc.y += v0.y;
            acc.z += v0.z;
            acc.w += v0.w;
        }
        float di = dinv[i];
        float4 y;
        y.x = fmaf(di, acc.x, b4.x);
        y.y = fmaf(di, acc.y, b4.y);
        y.z = fmaf(di, acc.z, b4.z);
        y.w = fmaf(di, acc.w, b4.w);
        *reinterpret_cast<float4*>(out + (size_t)i * F + fq) = y;
        if (STATS) {
            s[0] += y.x; sq[0] = fmaf(y.x, y.x, sq[0]);
            s[1] += y.y; sq[1] = fmaf(y.y, y.y, sq[1]);
            s[2] += y.z; sq[2] = fmaf(y.z, y.z, sq[2]);
            s[3] += y.w; sq[3] = fmaf(y.w, y.w, sq[3]);
        }
    }
    if (STATS) {
        __shared__ float sred[32][8];  // [lane][group]  (F==128 path only)
#pragma unroll
        for (int q = 0; q < 8; ++q) {
            float v = (q < 4) ? s[q] : sq[q - 4];
            sred[lane][grp] = v;
            __syncthreads();
            if (grp == 0) {
                float t = 0.f;
#pragma unroll
                for (int g = 0; g < 8; ++g) t += sred[lane][g];
                int f = fq + (q & 3);
                atomicAdd(stats + ((q < 4) ? f : 128 + f), t);
            }
            __syncthreads();
        }
    }
}

// scale = g * rsqrt(var+eps); shift = be - mean*scale
__global__ void finalize_kernel(const float* __restrict__ stats,
                                const float* __restrict__ g,
                                const float* __restrict__ be, float invn,
                                float* __restrict__ ss) {
    int f = threadIdx.x;
    float mean = stats[f] * invn;
    float var = fmaf(-mean, mean, stats[128 + f] * invn);
    float sc = g[f] * rsqrtf(var + 1e-5f);
    ss[f] = sc;
    ss[128 + f] = fmaf(-mean, sc, be[f]);
}

extern "C" void kernel_launch(void* const* d_in, const int* in_sizes, int n_in,
                              void* d_out, int out_size, void* d_ws,
                              size_t ws_size, hipStream_t stream) {
    const float* x   = (const float*)d_in[0];
    const int*   ei  = (const int*)d_in[1];
    const float* W1  = (const float*)d_in[2];
    const float* b1  = (const float*)d_in[3];
    const float* g1  = (const float*)d_in[4];
    const float* be1 = (const float*)d_in[5];
    const float* W2  = (const float*)d_in[6];
    const float* b2  = (const float*)d_in[7];
    const float* g2  = (const float*)d_in[8];
    const float* be2 = (const float*)d_in[9];
    const float* W3  = (const float*)d_in[10];
    const float* b3  = (const float*)d_in[11];
    float* out = (float*)d_out;

    const int n = in_sizes[0] / 128;
    const int E = in_sizes[1] / 2;
    const int* src = ei;
    const int* dst = ei + E;

    float* wsf    = (float*)d_ws;
    float* dinv   = wsf;                     // n floats
    float* stats  = wsf + n;                 // 256
    float* ss     = stats + 256;             // 256
    int*   rowptr = (int*)(ss + 256);        // n+1 ints
    int*   bsum   = rowptr + (n + 1);        // <=64 ints (scan block sums)
    int*   csrsrc = bsum + 64;               // E ints
    float* bufA   = (float*)(csrsrc + E);    // n*128
    float* bufB   = bufA + (size_t)n * 128;  // n*128

    const int total = n + 1;
    const int nb = (total + 2047) / 2048;    // scan chunks (25 for n=50000)

    // ---- CSR build + dinv ----
    hipMemsetAsync(rowptr, 0, (size_t)total * 4, stream);
    count_deg_kernel<<<(E + 255) / 256, 256, 0, stream>>>(dst, E, rowptr + 1);
    dinv_kernel<<<(n + 255) / 256, 256, 0, stream>>>(rowptr, n, dinv);
    scanA_kernel<<<nb, 256, 0, stream>>>(rowptr, total, bsum);
    scanB_kernel<<<1, 64, 0, stream>>>(bsum, nb);
    scanC_kernel<<<nb, 256, 0, stream>>>(rowptr, total, bsum);
    csr_build_kernel<<<(E + 255) / 256, 256, 0, stream>>>(src, dst, E, rowptr, csrsrc);

    dim3 gemmGrid128((n + 63) / 64, 2);
    dim3 gemmGrid64((n + 63) / 64, 1);

    // ---- layer 1 ----
    gemm_k128<128, false><<<gemmGrid128, 256, 0, stream>>>(x, W1, bufA, n, nullptr, dinv);
    hipMemsetAsync(stats, 0, 256 * 4, stream);
    aggregate_kernel<128, true><<<512, 256, 0, stream>>>(bufA, csrsrc, rowptr, dinv, b1, bufB, n, stats);
    finalize_kernel<<<1, 128, 0, stream>>>(stats, g1, be1, 1.0f / n, ss);

    // ---- layer 2 ----
    gemm_k128<128, true><<<gemmGrid128, 256, 0, stream>>>(bufB, W2, bufA, n, ss, dinv);
    hipMemsetAsync(stats, 0, 256 * 4, stream);
    aggregate_kernel<128, true><<<512, 256, 0, stream>>>(bufA, csrsrc, rowptr, dinv, b2, bufB, n, stats);
    finalize_kernel<<<1, 128, 0, stream>>>(stats, g2, be2, 1.0f / n, ss);

    // ---- layer 3 ----
    gemm_k128<64, true><<<gemmGrid64, 256, 0, stream>>>(bufB, W3, bufA, n, ss, dinv);
    aggregate_kernel<64, false><<<512, 256, 0, stream>>>(bufA, csrsrc, rowptr, dinv, b3, out, n, nullptr);
}